// Round 16
// baseline (895.640 us; speedup 1.0000x reference)
//
#include <hip/hip_runtime.h>
#include <hip/hip_bf16.h>

typedef __bf16 bf16_t;
typedef __bf16 bf16x8 __attribute__((ext_vector_type(8)));
typedef __bf16 bf16x4 __attribute__((ext_vector_type(4)));
typedef float f32x4 __attribute__((ext_vector_type(4)));
typedef int i32x4 __attribute__((ext_vector_type(4)));

__device__ __forceinline__ f32x4 mfma16(bf16x8 a, bf16x8 b, f32x4 c) {
  return __builtin_amdgcn_mfma_f32_16x16x32_bf16(a, b, c, 0, 0, 0);
}

__device__ __forceinline__ void gload16(const void* g, void* l) {
  __builtin_amdgcn_global_load_lds(
      (const __attribute__((address_space(1))) void*)g,
      (__attribute__((address_space(3))) void*)l, 16, 0, 0);
}

// ---------------- ternary threshold: deterministic fp64 reduction (fused, 6 weights) --------
__global__ void abssum_all(const float* __restrict__ W0, const float* __restrict__ W1_,
                           const float* __restrict__ W2_, const float* __restrict__ W3,
                           const float* __restrict__ W4, const float* __restrict__ W5,
                           double* __restrict__ partial) {
  __shared__ double sd[256];
  const int w = blockIdx.y, tid = threadIdx.x;
  const float* W = (w == 0) ? W0 : (w == 1) ? W1_ : (w == 2) ? W2_ : (w == 3) ? W3 : (w == 4) ? W4 : W5;
  const int n4 = (w < 4) ? 1048576 : 4194304;
  double s = 0.0;
  for (int i = blockIdx.x * 256 + tid; i < n4; i += 262144) {
    float4 v = ((const float4*)W)[i];
    s += (double)fabsf(v.x); s += (double)fabsf(v.y);
    s += (double)fabsf(v.z); s += (double)fabsf(v.w);
  }
  sd[tid] = s; __syncthreads();
  for (int st = 128; st > 0; st >>= 1) { if (tid < st) sd[tid] += sd[tid + st]; __syncthreads(); }
  if (tid == 0) partial[w * 1024 + blockIdx.x] = sd[0];
}

__global__ void abssum_fin(const double* __restrict__ partial, double* __restrict__ sums) {
  __shared__ double sd[256];
  const int tid = threadIdx.x;
  const double* p = partial + blockIdx.x * 1024;
  double s = p[tid] + p[tid + 256] + p[tid + 512] + p[tid + 768];
  sd[tid] = s; __syncthreads();
  for (int st = 128; st > 0; st >>= 1) { if (tid < st) sd[tid] += sd[tid + st]; __syncthreads(); }
  if (tid == 0) sums[blockIdx.x] = sd[0];
}

// ternarize Wq,Wk,Wv,Wo (4 x 4.19M elems) into one contiguous wt in a single launch
__global__ void ternarize4(const float* __restrict__ W0, const float* __restrict__ W1_,
                           const float* __restrict__ W2_, const float* __restrict__ W3,
                           bf16_t* __restrict__ out, const double* __restrict__ sums) {
  const int w = blockIdx.x >> 12;
  const float* W = (w == 0) ? W0 : (w == 1) ? W1_ : (w == 2) ? W2_ : W3;
  const double thr = sums[w] / 4194304.0;
  const int i = (blockIdx.x & 4095) * 256 + threadIdx.x;
  float4 v = ((const float4*)W)[i];
  bf16x4 o;
  float t;
  t = ((double)fabsf(v.x) > thr) ? (v.x > 0.f ? 1.f : -1.f) : 0.f; o[0] = (bf16_t)t;
  t = ((double)fabsf(v.y) > thr) ? (v.y > 0.f ? 1.f : -1.f) : 0.f; o[1] = (bf16_t)t;
  t = ((double)fabsf(v.z) > thr) ? (v.z > 0.f ? 1.f : -1.f) : 0.f; o[2] = (bf16_t)t;
  t = ((double)fabsf(v.w) > thr) ? (v.w > 0.f ? 1.f : -1.f) : 0.f; o[3] = (bf16_t)t;
  *(bf16x4*)&out[(size_t)w * 4194304 + (size_t)i * 4] = o;
}

__global__ void ternarize_k(const float* __restrict__ W, bf16_t* __restrict__ out,
                            const double* __restrict__ sum, double n) {
  const double thr = sum[0] / n;
  const int i = blockIdx.x * 256 + threadIdx.x;
  float4 v = ((const float4*)W)[i];
  bf16x4 o;
  float t;
  t = ((double)fabsf(v.x) > thr) ? (v.x > 0.f ? 1.f : -1.f) : 0.f; o[0] = (bf16_t)t;
  t = ((double)fabsf(v.y) > thr) ? (v.y > 0.f ? 1.f : -1.f) : 0.f; o[1] = (bf16_t)t;
  t = ((double)fabsf(v.z) > thr) ? (v.z > 0.f ? 1.f : -1.f) : 0.f; o[2] = (bf16_t)t;
  t = ((double)fabsf(v.w) > thr) ? (v.w > 0.f ? 1.f : -1.f) : 0.f; o[3] = (bf16_t)t;
  *(bf16x4*)&out[(size_t)i * 4] = o;
}

// ---------------- x -> interleaved hi/lo: xhl[t] = [ xh row (2048) | xl row (2048) ] ----------
__global__ void split_x_k(const float* __restrict__ X, bf16_t* __restrict__ xhl) {
  const int i = blockIdx.x * 256 + threadIdx.x;   // float4 idx; 512 per token row
  const int t = i >> 9, col = (i & 511) * 4;
  float4 v = ((const float4*)X)[i];
  bf16x4 h, l;
  h[0] = (bf16_t)v.x; l[0] = (bf16_t)(v.x - (float)h[0]);
  h[1] = (bf16_t)v.y; l[1] = (bf16_t)(v.y - (float)h[1]);
  h[2] = (bf16_t)v.z; l[2] = (bf16_t)(v.z - (float)h[2]);
  h[3] = (bf16_t)v.w; l[3] = (bf16_t)(v.w - (float)h[3]);
  *(bf16x4*)&xhl[(size_t)t * 4096 + col] = h;
  *(bf16x4*)&xhl[(size_t)t * 4096 + 2048 + col] = l;
}

// ---------------- GEMM v3: m201-style 2-phase (V only: transposed store) ----------------
template <int EPI>
__global__ __launch_bounds__(512, 2) void gemmP(
    const bf16_t* __restrict__ Ah, const bf16_t* __restrict__ Bw,
    void* __restrict__ C0, int N, int K, int lda) {
  constexpr int BM = 128;
  __shared__ __align__(16) bf16_t sA[3][BM * 64];
  __shared__ __align__(16) bf16_t sB[3][256 * 64];

  const int tid = threadIdx.x;
  const int wid = tid >> 6, lane = tid & 63, lr = lane & 15, lg = lane >> 4;
  const int wr = wid >> 2, wc = wid & 3;
  const size_t Ks = (size_t)K;

  const int nwg = gridDim.x * gridDim.y;
  const int bid0 = blockIdx.y * gridDim.x + blockIdx.x;
  const int swz = (bid0 & 7) * (nwg >> 3) + (bid0 >> 3);
  const int bx = swz % gridDim.x, by = swz / gridDim.x;
  const size_t m0 = (size_t)by * BM, n0 = (size_t)bx * 256;
  const int nt = K / 64;

  f32x4 acc[4][4] = {};

  auto STAGEH = [&](int bi, int kt, int half) {
    const size_t ko = (size_t)kt * 64;
    if (half == 0) {
#pragma unroll
      for (int i = 0; i < 2; i++) {
        const int t = i * 512 + tid;
        const int r = t >> 3;
        const int su = (t & 7) ^ (r & 7);
        const int lo = (i * 512 + wid * 64) * 8;
        gload16(Ah + (m0 + r) * (size_t)lda + ko + su * 8, (void*)&sA[bi][lo]);
      }
      {
        const int r = tid >> 3;
        const int su = (tid & 7) ^ (r & 7);
        gload16(Bw + (n0 + r) * Ks + ko + su * 8, (void*)&sB[bi][(wid * 64) * 8]);
      }
    } else {
#pragma unroll
      for (int i = 1; i < 4; i++) {
        const int t = i * 512 + tid;
        const int r = t >> 3;
        const int su = (t & 7) ^ (r & 7);
        gload16(Bw + (n0 + r) * Ks + ko + su * 8, (void*)&sB[bi][(i * 512 + wid * 64) * 8]);
      }
    }
  };
  auto LDA = [&](const bf16_t* base, int m, int k) -> bf16x8 {
    const int row = wr * 64 + m * 16 + lr;
    const int u = (k * 4 + lg) ^ (lr & 7);
    return *(const bf16x8*)&base[row * 64 + u * 8];
  };
  auto LDB = [&](const bf16_t* base, int n, int k) -> bf16x8 {
    const int row = wc * 64 + n * 16 + lr;
    const int u = (k * 4 + lg) ^ (lr & 7);
    return *(const bf16x8*)&base[row * 64 + u * 8];
  };

  STAGEH(0, 0, 0); STAGEH(0, 0, 1);
  STAGEH(1, 1, 0); STAGEH(1, 1, 1);
  asm volatile("s_waitcnt vmcnt(6)" ::: "memory");
  __builtin_amdgcn_s_barrier();

  int bc = 0, bs = 2;
  for (int kt = 0; kt < nt; kt++) {
    const bool pf = (kt + 2 < nt);
    bf16x8 a[4][2], bfr[4][2];
#pragma unroll
    for (int m = 0; m < 4; m++)
#pragma unroll
      for (int k = 0; k < 2; k++) a[m][k] = LDA(&sA[bc][0], m, k);
#pragma unroll
    for (int n = 0; n < 2; n++)
#pragma unroll
      for (int k = 0; k < 2; k++) bfr[n][k] = LDB(&sB[bc][0], n, k);
    if (pf) STAGEH(bs, kt + 2, 0);
    __builtin_amdgcn_s_barrier();
    asm volatile("s_waitcnt lgkmcnt(0)" ::: "memory");
    __builtin_amdgcn_sched_barrier(0);
    __builtin_amdgcn_s_setprio(1);
#pragma unroll
    for (int k = 0; k < 2; k++)
#pragma unroll
      for (int m = 0; m < 4; m++)
#pragma unroll
        for (int n = 0; n < 2; n++) acc[m][n] = mfma16(a[m][k], bfr[n][k], acc[m][n]);
    __builtin_amdgcn_s_setprio(0);
    __builtin_amdgcn_s_barrier();
#pragma unroll
    for (int n = 0; n < 2; n++)
#pragma unroll
      for (int k = 0; k < 2; k++) bfr[n + 2][k] = LDB(&sB[bc][0], n + 2, k);
    if (pf) STAGEH(bs, kt + 2, 1);
    if (kt + 1 < nt) {
      if (pf) asm volatile("s_waitcnt vmcnt(6)" ::: "memory");
      else    asm volatile("s_waitcnt vmcnt(0)" ::: "memory");
    }
    __builtin_amdgcn_s_barrier();
    asm volatile("s_waitcnt lgkmcnt(0)" ::: "memory");
    __builtin_amdgcn_sched_barrier(0);
    __builtin_amdgcn_s_setprio(1);
#pragma unroll
    for (int k = 0; k < 2; k++)
#pragma unroll
      for (int m = 0; m < 4; m++)
#pragma unroll
        for (int n = 0; n < 2; n++) acc[m][n + 2] = mfma16(a[m][k], bfr[n + 2][k], acc[m][n + 2]);
    __builtin_amdgcn_s_setprio(0);
    __builtin_amdgcn_s_barrier();
    bc = (bc + 1 == 3) ? 0 : bc + 1;
    bs = (bs + 1 == 3) ? 0 : bs + 1;
  }

  const int row0 = (int)m0 + wr * 64, colb = (int)n0 + wc * 64;
#pragma unroll
  for (int m = 0; m < 4; m++)
#pragma unroll
    for (int n = 0; n < 4; n++)
#pragma unroll
      for (int j = 0; j < 4; j++) {
        const int r = row0 + m * 16 + lg * 4 + j;
        const int c = colb + n * 16 + lr;
        const float v = acc[m][n][j];
        if constexpr (EPI == 1) {
          const int bb = r >> 11, ss = r & 2047;
          ((bf16_t*)C0)[((size_t)bb * 2048 + c) * 2048 + ss] = (bf16_t)v;
        } else {
          ((float*)C0)[(size_t)r * N + c] = v;
        }
      }
}

// ---------------- GEMM 256x256, 8-phase m201 schedule (QK / FF1 / O,FF2 split-K) ----------
// EPI: 0 = split hi/lo bf16 (stride N), 3 = relu bf16, 4 = f32 to (kh? C1 : C0).
template <int EPI, int MB>
__global__ __launch_bounds__(512, 2) void gemm256(
    const bf16_t* __restrict__ A, const bf16_t* __restrict__ Bw,
    void* __restrict__ C0, void* __restrict__ C1,
    int N, int K, int lda, int ldb) {
  __shared__ __align__(16) bf16_t sA[2][256 * 64];
  __shared__ __align__(16) bf16_t sB[2][256 * 64];
  const int tid = threadIdx.x;
  const int wid = tid >> 6, lane = tid & 63, lr = lane & 15, lg = lane >> 4;
  const int wr = wid >> 2, wc = wid & 3;   // 2M x 4N waves; per-wave 128x64
  const int nwg = gridDim.x * gridDim.y;
  const int bid0 = blockIdx.y * gridDim.x + blockIdx.x;
  const int swz = (bid0 & 7) * (nwg >> 3) + (bid0 >> 3);
  const int bx = swz % gridDim.x, by = swz / gridDim.x;
  const int mt = by & ((1 << MB) - 1), kh = by >> MB;
  const int koff = kh * K;
  const size_t m0 = (size_t)mt * 256, n0 = (size_t)bx * 256;
  const int nt = K / 64;
  const bf16_t* Abase = A + m0 * (size_t)lda;
  const bf16_t* Bbase = Bw + n0 * (size_t)ldb;

  f32x4 acc[8][4] = {};

  auto SG = [&](const bf16_t* base, bf16_t* dst, int kt, int h, int ld) {
    const size_t co = (size_t)((kt * 64 + koff) & (ld - 1));
#pragma unroll
    for (int i = 0; i < 2; i++) {
      const int e = (2 * h + i) * 512 + tid;
      const int r = e >> 3;
      const int su = (tid & 7) ^ (r & 7);
      gload16(base + (size_t)r * ld + co + su * 8,
              (void*)&dst[((2 * h + i) * 512 + wid * 64) * 8]);
    }
  };
  auto LDA = [&](int bi, int m, int k) -> bf16x8 {
    const int row = wr * 128 + m * 16 + lr;
    const int u = (k * 4 + lg) ^ (lr & 7);
    return *(const bf16x8*)&sA[bi][row * 64 + u * 8];
  };
  auto LDB = [&](int bi, int n, int k) -> bf16x8 {
    const int row = wc * 64 + n * 16 + lr;
    const int u = (k * 4 + lg) ^ (lr & 7);
    return *(const bf16x8*)&sB[bi][row * 64 + u * 8];
  };

  // prologue: tile0 full; tile1 B0,B1,A0 (A1 comes at kt0.Q1)
  SG(Abase, sA[0], 0, 0, lda); SG(Abase, sA[0], 0, 1, lda);
  SG(Bbase, sB[0], 0, 0, ldb); SG(Bbase, sB[0], 0, 1, ldb);
  SG(Bbase, sB[1], 1, 0, ldb); SG(Bbase, sB[1], 1, 1, ldb); SG(Abase, sA[1], 1, 0, lda);
  asm volatile("s_waitcnt vmcnt(6)" ::: "memory");
  __builtin_amdgcn_s_barrier();

  for (int kt = 0; kt < nt; kt++) {
    const int bi = kt & 1, bn = bi ^ 1;
    bf16x8 a[4][2], b[4][2];
    // ---- Q1: m0-3 x n0-1 ----
#pragma unroll
    for (int m = 0; m < 4; m++)
#pragma unroll
      for (int k = 0; k < 2; k++) a[m][k] = LDA(bi, m, k);
#pragma unroll
    for (int n = 0; n < 2; n++)
#pragma unroll
      for (int k = 0; k < 2; k++) b[n][k] = LDB(bi, n, k);
    if (kt + 1 < nt) SG(Abase, sA[bn], kt + 1, 1, lda);   // deferred A1 of next tile
    __builtin_amdgcn_s_barrier();
    asm volatile("s_waitcnt lgkmcnt(0)" ::: "memory");
    __builtin_amdgcn_sched_barrier(0);
    __builtin_amdgcn_s_setprio(1);
#pragma unroll
    for (int k = 0; k < 2; k++)
#pragma unroll
      for (int m = 0; m < 4; m++)
#pragma unroll
        for (int n = 0; n < 2; n++) acc[m][n] = mfma16(a[m][k], b[n][k], acc[m][n]);
    __builtin_amdgcn_s_setprio(0);
    __builtin_amdgcn_s_barrier();
    // ---- Q2: m0-3 x n2-3 ----
#pragma unroll
    for (int n = 0; n < 2; n++)
#pragma unroll
      for (int k = 0; k < 2; k++) b[n + 2][k] = LDB(bi, n + 2, k);
    if (kt + 2 < nt) SG(Bbase, sB[bi], kt + 2, 0, ldb);
    __builtin_amdgcn_s_barrier();
    asm volatile("s_waitcnt lgkmcnt(0)" ::: "memory");
    __builtin_amdgcn_sched_barrier(0);
    __builtin_amdgcn_s_setprio(1);
#pragma unroll
    for (int k = 0; k < 2; k++)
#pragma unroll
      for (int m = 0; m < 4; m++)
#pragma unroll
        for (int n = 0; n < 2; n++) acc[m][n + 2] = mfma16(a[m][k], b[n + 2][k], acc[m][n + 2]);
    __builtin_amdgcn_s_setprio(0);
    __builtin_amdgcn_s_barrier();
    // ---- Q3: m4-7 x n2-3 ----
#pragma unroll
    for (int m = 0; m < 4; m++)
#pragma unroll
      for (int k = 0; k < 2; k++) a[m][k] = LDA(bi, m + 4, k);
    if (kt + 2 < nt) SG(Bbase, sB[bi], kt + 2, 1, ldb);
    __builtin_amdgcn_s_barrier();
    asm volatile("s_waitcnt lgkmcnt(0)" ::: "memory");
    __builtin_amdgcn_sched_barrier(0);
    __builtin_amdgcn_s_setprio(1);
#pragma unroll
    for (int k = 0; k < 2; k++)
#pragma unroll
      for (int m = 0; m < 4; m++)
#pragma unroll
        for (int n = 0; n < 2; n++) acc[m + 4][n + 2] = mfma16(a[m][k], b[n + 2][k], acc[m + 4][n + 2]);
    __builtin_amdgcn_s_setprio(0);
    __builtin_amdgcn_s_barrier();
    // ---- Q4: m4-7 x n0-1 (a,b already in regs) ----
    if (kt + 2 < nt) SG(Abase, sA[bi], kt + 2, 0, lda);
    __builtin_amdgcn_s_setprio(1);
#pragma unroll
    for (int k = 0; k < 2; k++)
#pragma unroll
      for (int m = 0; m < 4; m++)
#pragma unroll
        for (int n = 0; n < 2; n++) acc[m + 4][n] = mfma16(a[m][k], b[n][k], acc[m + 4][n]);
    __builtin_amdgcn_s_setprio(0);
    if (kt + 1 < nt) {
      if (kt + 2 < nt) asm volatile("s_waitcnt vmcnt(6)" ::: "memory");
      else             asm volatile("s_waitcnt vmcnt(0)" ::: "memory");
    }
    __builtin_amdgcn_s_barrier();
  }

  const int row0 = (int)m0 + wr * 128, colb = (int)n0 + wc * 64;
#pragma unroll
  for (int m = 0; m < 8; m++)
#pragma unroll
    for (int n = 0; n < 4; n++)
#pragma unroll
      for (int j = 0; j < 4; j++) {
        const int r = row0 + m * 16 + lg * 4 + j;
        const int c = colb + n * 16 + lr;
        const float v = acc[m][n][j];
        if constexpr (EPI == 0) {
          bf16_t hi = (bf16_t)v;
          ((bf16_t*)C0)[(size_t)r * N + c] = hi;
          ((bf16_t*)C1)[(size_t)r * N + c] = (bf16_t)(v - (float)hi);
        } else if constexpr (EPI == 4) {
          float* dst = (float*)(kh ? C1 : C0);
          dst[(size_t)r * N + c] = v;
        } else {
          ((bf16_t*)C0)[(size_t)r * N + c] = (bf16_t)fmaxf(v, 0.f);
        }
      }
}

// ---------------- flash attention v12: v10 + T15 2-chunk double-pipeline ----------------
// Two S register sets (sA/sB): QK(c+1) MFMAs share a scheduling region with
// softmax(c)'s VALU chain (independent dataflow) so the wave's pipes overlap.
// Barrier discipline per half: STAGE(c+2) -> vmcnt(8) -> barrier -> QK(c+1)
// -> softmax+PV(c) (drain covers QK ds_reads) -> barrier.
__global__ __launch_bounds__(256, 2) void attn_k(
    const bf16_t* __restrict__ qh, const bf16_t* __restrict__ ql,
    const bf16_t* __restrict__ kh, const bf16_t* __restrict__ kl,
    const bf16_t* __restrict__ vT, bf16_t* __restrict__ out) {
  __shared__ __align__(16) bf16_t sKh[2 * 8192];   // 2 x [64][128]; epilogue scratch
  __shared__ __align__(16) bf16_t sKl[2 * 8192];
  __shared__ __align__(16) bf16_t plds[4][2048];   // per-wave P [2 tiles][16 q][64 kv]

  const int fid = blockIdx.y * 16 + blockIdx.x;
  const int qt = fid >> 5;
  const int bh = (fid & 7) * 4 + ((fid >> 3) & 3);
  const int b = bh >> 4, h = bh & 15;
  const int wv = threadIdx.x >> 6, lane = threadIdx.x & 63, lr = lane & 15, lg = lane >> 4;
  const size_t tok0 = (size_t)b * 2048 + qt * 128 + wv * 16;  // tile0; tile1 = +64
  bf16_t* pw = &plds[wv][0];

  auto STAGE = [&](int bufi, int kv0n) {
#pragma unroll
    for (int i = 0; i < 4; i++) {
      const int tt = wv * 4 + i;
      const int r = tt * 4 + (lane >> 4);
      const int ce = ((lane & 15) ^ (r & 7)) * 8;
      const size_t gofs = ((size_t)b * 2048 + kv0n + r) * 4096 + h * 128 + ce;
      gload16(kh + gofs, (void*)&sKh[bufi * 8192 + tt * 512]);
      gload16(kl + gofs, (void*)&sKl[bufi * 8192 + tt * 512]);
    }
  };

  bf16x8 qhf[2][4], qlf[2][4];
#pragma unroll
  for (int t = 0; t < 2; t++) {
    const bf16_t* qp = qh + (tok0 + t * 64 + lr) * 4096 + h * 128 + lg * 8;
    const bf16_t* qp2 = ql + (tok0 + t * 64 + lr) * 4096 + h * 128 + lg * 8;
#pragma unroll
    for (int ks = 0; ks < 4; ks++) {
      qhf[t][ks] = *(const bf16x8*)(qp + ks * 32);
      qlf[t][ks] = *(const bf16x8*)(qp2 + ks * 32);
    }
  }
  f32x4 oacc[2][8] = {};           // [tile][dt]: row d=dt*16+lg*4+j, col q=lr
  float mrun[2] = {-1e30f, -1e30f};
  float lrun[2] = {0.f, 0.f};
  const bf16_t* vbase = vT + ((size_t)b * 2048 + h * 128) * 2048;
  const float sc = 0.08838834764831845f;
  const int swz8 = 2 * (lr & 7);

  // QK of one chunk from LDS buffer at byte/elem offset bufo into s (zeroed)
  auto QKc = [&](int bufo, f32x4 (&s)[2][4]) {
    const f32x4 zz = {0.f, 0.f, 0.f, 0.f};
#pragma unroll
    for (int t = 0; t < 2; t++)
#pragma unroll
      for (int nb = 0; nb < 4; nb++) s[t][nb] = zz;
#pragma unroll
    for (int nb = 0; nb < 4; nb++) {
      const int rbase = bufo + (nb * 16 + lr) * 128;
#pragma unroll
      for (int ks = 0; ks < 4; ks++) {
        const int u = (((ks * 4 + lg) ^ (lr & 7)) * 8);
        bf16x8 kf = *(const bf16x8*)&sKh[rbase + u];
        bf16x8 kg = *(const bf16x8*)&sKl[rbase + u];
        s[0][nb] = mfma16(kf, qhf[0][ks], s[0][nb]);
        s[1][nb] = mfma16(kf, qhf[1][ks], s[1][nb]);
        s[0][nb] = mfma16(kf, qlf[0][ks], s[0][nb]);
        s[1][nb] = mfma16(kf, qlf[1][ks], s[1][nb]);
        s[0][nb] = mfma16(kg, qhf[0][ks], s[0][nb]);
        s[1][nb] = mfma16(kg, qhf[1][ks], s[1][nb]);
      }
    }
  };

  // softmax + P pack + PV for one chunk from its s registers
  auto SMPV = [&](int kv0, f32x4 (&s)[2][4]) {
    float resc[2];
    bool skip[2];
#pragma unroll
    for (int t = 0; t < 2; t++) {
#pragma unroll
      for (int nb = 0; nb < 4; nb++) s[t][nb] *= sc;
      f32x4 m4 = __builtin_elementwise_max(
          __builtin_elementwise_max(s[t][0], s[t][1]),
          __builtin_elementwise_max(s[t][2], s[t][3]));
      float mx = fmaxf(fmaxf(m4[0], m4[1]), fmaxf(m4[2], m4[3]));
      mx = fmaxf(mx, __shfl_xor(mx, 16));
      mx = fmaxf(mx, __shfl_xor(mx, 32));
      skip[t] = (__all(mx <= mrun[t] + 8.f) != 0);  // defer-max (THR=8)
      float rs_ = 1.f;
      if (!skip[t]) {
        const float mnew = fmaxf(mrun[t], mx);
        rs_ = __expf(mrun[t] - mnew);
        mrun[t] = mnew;
      }
      resc[t] = rs_;
      float ls = 0.f;
#pragma unroll
      for (int nb = 0; nb < 4; nb++) {
        bf16x4 pk;
#pragma unroll
        for (int j = 0; j < 4; j++) {
          const float p = __expf(s[t][nb][j] - mrun[t]);
          ls += p;
          pk[j] = (bf16_t)p;
        }
        const int s8 = (4 * nb + lg) ^ swz8;
        *(bf16x4*)&pw[t * 1024 + lr * 64 + s8 * 4] = pk;
      }
      ls += __shfl_xor(ls, 16);
      ls += __shfl_xor(ls, 32);
      lrun[t] = lrun[t] * rs_ + ls;
    }
    asm volatile("s_waitcnt lgkmcnt(0)" ::: "memory");
    __builtin_amdgcn_sched_barrier(0);
    bf16x8 pfr[2][2];
#pragma unroll
    for (int t = 0; t < 2; t++)
#pragma unroll
      for (int kc = 0; kc < 2; kc++) {
        const int se = (8 * kc + 2 * lg) ^ swz8;
        pfr[t][kc] = *(const bf16x8*)&pw[t * 1024 + lr * 64 + se * 4];
      }
    if (!skip[0]) {
#pragma unroll
      for (int dt = 0; dt < 8; dt++) oacc[0][dt] *= resc[0];
    }
    if (!skip[1]) {
#pragma unroll
      for (int dt = 0; dt < 8; dt++) oacc[1][dt] *= resc[1];
    }
    const bf16_t* vp = vbase + kv0 + lg * 8;
    __builtin_amdgcn_s_setprio(1);
#pragma unroll
    for (int dt = 0; dt < 8; dt++) {
      const bf16_t* vr = vp + (size_t)(dt * 16 + lr) * 2048;
      bf16x8 v0 = *(const bf16x8*)(vr);
      bf16x8 v1 = *(const bf16x8*)(vr + 32);
      oacc[0][dt] = mfma16(v0, pfr[0][0], oacc[0][dt]);
      oacc[1][dt] = mfma16(v0, pfr[1][0], oacc[1][dt]);
      oacc[0][dt] = mfma16(v1, pfr[0][1], oacc[0][dt]);
      oacc[1][dt] = mfma16(v1, pfr[1][1], oacc[1][dt]);
    }
    __builtin_amdgcn_s_setprio(0);
    asm volatile("" ::: "memory");
  };

  f32x4 sA[2][4], sB[2][4];
  // prologue: stage(0), publish; stage(1) in flight; QK(0) -> sA
  STAGE(0, 0);
  asm volatile("s_waitcnt vmcnt(0)" ::: "memory");
  __builtin_amdgcn_s_barrier();
  STAGE(1, 64);
  QKc(0, sA);
  asm volatile("s_waitcnt lgkmcnt(0)" ::: "memory");
  __builtin_amdgcn_s_barrier();              // all waves past QK(0): buf0 reusable

  for (int i = 0; i < 16; i++) {
    const int c0 = 2 * i, c1 = 2 * i + 1;
    // ---- half A: compute QK(c1), finish chunk c0 ----
    if (c0 + 2 < 32) {
      STAGE(0, (c0 + 2) * 64);
      asm volatile("s_waitcnt vmcnt(8)" ::: "memory");  // stage(c1) done
    } else {
      asm volatile("s_waitcnt vmcnt(0)" ::: "memory");
    }
    __builtin_amdgcn_s_barrier();            // stage(c1) visible
    QKc(8192, sB);                           // MFMA: overlaps softmax(c0) below
    SMPV(c0 * 64, sA);                       // VALU + P-LDS + PV
    __builtin_amdgcn_s_barrier();            // buf1 reads drained (SMPV drain covers)
    // ---- half B: compute QK(c0+2), finish chunk c1 ----
    if (c1 + 2 < 32) {
      STAGE(1, (c1 + 2) * 64);
      asm volatile("s_waitcnt vmcnt(8)" ::: "memory");  // stage(c0+2) done
    } else {
      asm volatile("s_waitcnt vmcnt(0)" ::: "memory");
    }
    __builtin_amdgcn_s_barrier();
    if (i < 15) QKc(0, sA);
    SMPV(c1 * 64, sB);
    __builtin_amdgcn_s_barrier();
  }

  // ---- epilogue: padded per-wave transpose region in sKh (K data dead) ----
  {
    bf16_t* ep = &sKh[wv * 2176];                // [16 q][136 pad] bf16
    const int q = lane >> 2, c4 = lane & 3;
    const int qs = 2 * (q & 7);
#pragma unroll
    for (int t = 0; t < 2; t++) {
      const float inv = 1.f / lrun[t];
#pragma unroll
      for (int dt = 0; dt < 8; dt++) {
        bf16x4 pk;
#pragma unroll
        for (int j = 0; j < 4; j++) pk[j] = (bf16_t)(oacc[t][dt][j] * inv);
        const int s5 = (4 * dt + lg) ^ swz8;
        *(bf16x4*)&ep[lr * 136 + s5 * 4] = pk;
      }
      asm volatile("s_waitcnt lgkmcnt(0)" ::: "memory");
      __builtin_amdgcn_sched_barrier(0);
      bf16_t* orow = out + (tok0 + t * 64 + q) * 2048 + h * 128 + c4 * 32;
#pragma unroll
      for (int i = 0; i < 4; i++) {
        const int se = (c4 * 8 + 2 * i) ^ qs;
        bf16x8 vv = *(const bf16x8*)&ep[q * 136 + se * 4];
        *(bf16x8*)(orow + i * 8) = vv;
      }
      asm volatile("s_waitcnt lgkmcnt(0)" ::: "memory");
    }
  }
}

// ---------------- LN1: f32 X + two f32 residual partials -> bf16 out ----------------
__global__ __launch_bounds__(256) void ln1_k(
    const float* __restrict__ X, const float* __restrict__ R0, const float* __restrict__ R1,
    const float* __restrict__ G, const float* __restrict__ Bt, bf16_t* __restrict__ O16) {
  const int t = blockIdx.x, tid = threadIdx.x;
  const float4* xp = (const float4*)(X + (size_t)t * 2048);
  const float4* r0p = (const float4*)(R0 + (size_t)t * 2048);
  const float4* r1p = (const float4*)(R1 + (size_t)t * 2048);
  float4 v0 = xp[tid], v1 = xp[tid + 256];
  float4 a0 = r0p[tid], a1 = r0p[tid + 256];
  float4 c0 = r1p[tid], c1 = r1p[tid + 256];
  v0.x += a0.x + c0.x; v0.y += a0.y + c0.y; v0.z += a0.z + c0.z; v0.w += a0.w + c0.w;
  v1.x += a1.x + c1.x; v1.y += a1.y + c1.y; v1.z += a1.z + c1.z; v1.w += a1.w + c1.w;
  float sum = v0.x + v0.y + v0.z + v0.w + v1.x + v1.y + v1.z + v1.w;
  float sq = v0.x * v0.x + v0.y * v0.y + v0.z * v0.z + v0.w * v0.w +
             v1.x * v1.x + v1.y * v1.y + v1.z * v1.z + v1.w * v1.w;
  for (int d = 1; d < 64; d <<= 1) { sum += __shfl_xor(sum, d); sq += __shfl_xor(sq, d); }
  __shared__ float s1[4], s2[4];
  const int wv = tid >> 6, lane = tid & 63;
  if (lane == 0) { s1[wv] = sum; s2[wv] = sq; }
  __syncthreads();
  const float tot = s1[0] + s1[1] + s1[2] + s1[3];
  const float tsq = s2[0] + s2[1] + s2[2] + s2[3];
  const float mu = tot * (1.f / 2048.f);
  const float var = tsq * (1.f / 2048.f) - mu * mu;
  const float rs = 1.f / sqrtf(var + 1e-5f);
  const float4* gp = (const float4*)G;
  const float4* bp = (const float4*)Bt;
  float4 g0 = gp[tid], g1v = gp[tid + 256], b0 = bp[tid], b1v = bp[tid + 256];
  bf16x4 h0, h1;
  h0[0] = (bf16_t)((v0.x - mu) * rs * g0.x + b0.x);
  h0[1] = (bf16_t)((v0.y - mu) * rs * g0.y + b0.y);
  h0[2] = (bf16_t)((v0.z - mu) * rs * g0.z + b0.z);
  h0[3] = (bf16_t)((v0.w - mu) * rs * g0.w + b0.w);
  h1[0] = (bf16_t)((v1.x - mu) * rs * g1v.x + b1v.x);
  h1[1] = (bf16_t)((v1.y - mu) * rs * g1v.y + b1v.y);
  h1[2] = (bf16_t)((v1.z - mu) * rs * g1v.z + b1v.z);
  h1[3] = (bf16_t)((v1.w - mu) * rs * g1v.w + b1v.w);
  *(bf16x4*)&O16[(size_t)t * 2048 + tid * 4] = h0;
  *(bf16x4*)&O16[(size_t)t * 2048 + 1024 + tid * 4] = h1;
}

// ---------------- LN2: bf16 X + two f32 residual partials -> f32 out ----------------
__global__ __launch_bounds__(256) void ln2_k(
    const bf16_t* __restrict__ Xb, const float* __restrict__ R0, const float* __restrict__ R1,
    const float* __restrict__ G, const float* __restrict__ Bt, float* __restrict__ out) {
  const int t = blockIdx.x, tid = threadIdx.x;
  bf16x4 x0 = *(const bf16x4*)&Xb[(size_t)t * 2048 + tid * 4];
  bf16x4 x1 = *(const bf16x4*)&Xb[(size_t)t * 2048 + 1024 + tid * 4];
  const float4* r0p = (const float4*)(R0 + (size_t)t * 2048);
  const float4* r1p = (const float4*)(R1 + (size_t)t * 2048);
  float4 a0 = r0p[tid], a1 = r0p[tid + 256];
  float4 c0 = r1p[tid], c1 = r1p[tid + 256];
  float4 v0, v1;
  v0.x = (float)x0[0] + a0.x + c0.x; v0.y = (float)x0[1] + a0.y + c0.y;
  v0.z = (float)x0[2] + a0.z + c0.z; v0.w = (float)x0[3] + a0.w + c0.w;
  v1.x = (float)x1[0] + a1.x + c1.x; v1.y = (float)x1[1] + a1.y + c1.y;
  v1.z = (float)x1[2] + a1.z + c1.z; v1.w = (float)x1[3] + a1.w + c1.w;
  float sum = v0.x + v0.y + v0.z + v0.w + v1.x + v1.y + v1.z + v1.w;
  float sq = v0.x * v0.x + v0.y * v0.y + v0.z * v0.z + v0.w * v0.w +
             v1.x * v1.x + v1.y * v1.y + v1.z * v1.z + v1.w * v1.w;
  for (int d = 1; d < 64; d <<= 1) { sum += __shfl_xor(sum, d); sq += __shfl_xor(sq, d); }
  __shared__ float s1[4], s2[4];
  const int wv = tid >> 6, lane = tid & 63;
  if (lane == 0) { s1[wv] = sum; s2[wv] = sq; }
  __syncthreads();
  const float tot = s1[0] + s1[1] + s1[2] + s1[3];
  const float tsq = s2[0] + s2[1] + s2[2] + s2[3];
  const float mu = tot * (1.f / 2048.f);
  const float var = tsq * (1.f / 2048.f) - mu * mu;
  const float rs = 1.f / sqrtf(var + 1e-5f);
  const float4* gp = (const float4*)G;
  const float4* bp = (const float4*)Bt;
  float4 g0 = gp[tid], g1v = gp[tid + 256], b0 = bp[tid], b1v = bp[tid + 256];
  float4 o0, o1;
  o0.x = (v0.x - mu) * rs * g0.x + b0.x; o0.y = (v0.y - mu) * rs * g0.y + b0.y;
  o0.z = (v0.z - mu) * rs * g0.z + b0.z; o0.w = (v0.w - mu) * rs * g0.w + b0.w;
  o1.x = (v1.x - mu) * rs * g1v.x + b1v.x; o1.y = (v1.y - mu) * rs * g1v.y + b1v.y;
  o1.z = (v1.z - mu) * rs * g1v.z + b1v.z; o1.w = (v1.w - mu) * rs * g1v.w + b1v.w;
  ((float4*)(out + (size_t)t * 2048))[tid] = o0;
  ((float4*)(out + (size_t)t * 2048))[tid + 256] = o1;
}

// ---------------- launch ----------------
extern "C" void kernel_launch(void* const* d_in, const int* in_sizes, int n_in,
                              void* d_out, int out_size, void* d_ws, size_t ws_size,
                              hipStream_t stream) {
  const float* x  = (const float*)d_in[0];
  const float* Wq = (const float*)d_in[1];
  const float* Wk = (const float*)d_in[2];
  const float* Wv = (const float*)d_in[3];
  const float* Wo = (const float*)d_in[4];
  const float* W1 = (const float*)d_in[5];
  const float* W2 = (const float*)d_in[6];
  const float* g1 = (const float*)d_in[7];
  const float* b1 = (const float*)d_in[8];
  const float* g2 = (const float*)d_in[9];
  const float* b2 = (const float*)d_in[10];
  float* out = (float*)d_out;
  char* ws = (char*)d_ws;

  constexpr size_t SZB = (size_t)4096 * 2048 * 2;  // 16.78 MB unit
  bf16_t* xhl = (bf16_t*)(ws + 0 * SZB);   // [4096][4096]; dead after V GEMM
  bf16_t* qkh = (bf16_t*)(ws + 2 * SZB);   // [4096][4096]: q | k (hi)
  bf16_t* qkl = (bf16_t*)(ws + 4 * SZB);   // same layout (lo)
  bf16_t* vt  = (bf16_t*)(ws + 6 * SZB);
  bf16_t* at  = (bf16_t*)(ws + 7 * SZB);
  float* o32  = (float*)(ws + 8 * SZB);
  bf16_t* wt  = (bf16_t*)(ws + 8 * SZB + (size_t)4096 * 2048 * 4);
  double* red = (double*)(ws + 8 * SZB + (size_t)4096 * 2048 * 4 + (size_t)8192 * 2048 * 2);
  double* sums = red + 8192;
  // aliases (phase-disjoint lifetimes)
  bf16_t* h1b = qkh;                       // over qkh (dead after attn)
  bf16_t* f1 = (bf16_t*)(ws + 4 * SZB);    // over qkl,vt,at (dead after O-proj)
  float* p0 = o32;                         // partial buffer A (slots 8-9)
  float* p1 = (float*)(ws + 0 * SZB);      // partial buffer B (over xhl, dead)
  (void)in_sizes; (void)n_in; (void)out_size; (void)ws_size;

  abssum_all<<<dim3(1024, 6), 256, 0, stream>>>(Wq, Wk, Wv, Wo, W1, W2, red);
  abssum_fin<<<6, 256, 0, stream>>>(red, sums);
  split_x_k<<<8192, 256, 0, stream>>>(x, xhl);
  ternarize4<<<16384, 256, 0, stream>>>(Wq, Wk, Wv, Wo, wt, sums);

  // merged Q+K via K-folding: A=[xh|xl] (lda 4096, K=4096), B wraps mod 2048
  gemm256<0, 8><<<dim3(16, 16), 512, 0, stream>>>(xhl, wt, qkh, qkl, 4096, 4096, 4096, 2048);
  // V (hi-only: K=2048 reads xh half of xhl; transposed store)
  gemmP<1><<<dim3(8, 32), 512, 0, stream>>>(xhl, wt + 8388608, vt, 2048, 2048, 4096);
  // attention
  attn_k<<<dim3(16, 32), 256, 0, stream>>>(qkh, qkl, qkh + 2048, qkl + 2048, vt, at);
  // O projection: split-K x2 (K=1024 each), full chip -> partials p0/p1
  gemm256<4, 4><<<dim3(8, 32), 512, 0, stream>>>(at, wt + 12582912, p0, p1, 2048, 1024, 2048, 2048);
  // LN1: x + p0 + p1 -> h1b (bf16)
  ln1_k<<<4096, 256, 0, stream>>>(x, p0, p1, g1, b1, h1b);
  // FF1 + relu (256x256 8-phase)
  ternarize_k<<<16384, 256, 0, stream>>>(W1, wt, sums + 4, 16777216.0);
  gemm256<3, 8><<<dim3(32, 16), 512, 0, stream>>>(h1b, wt, f1, nullptr, 8192, 2048, 2048, 2048);
  // FF2 split-K (two 4096-halves, full chip): partials -> p0 / p1
  ternarize_k<<<16384, 256, 0, stream>>>(W2, wt, sums + 5, 16777216.0);
  gemm256<4, 4><<<dim3(8, 32), 512, 0, stream>>>(f1, wt, p0, p1, 2048, 4096, 8192, 8192);
  // LN2: h1b + p0 + p1 -> out
  ln2_k<<<4096, 256, 0, stream>>>(h1b, p0, p1, g2, b2, out);
}

// Round 17
// 779.875 us; speedup vs baseline: 1.1484x; 1.1484x over previous
//
#include <hip/hip_runtime.h>
#include <hip/hip_bf16.h>

typedef __bf16 bf16_t;
typedef __bf16 bf16x8 __attribute__((ext_vector_type(8)));
typedef __bf16 bf16x4 __attribute__((ext_vector_type(4)));
typedef float f32x4 __attribute__((ext_vector_type(4)));
typedef int i32x4 __attribute__((ext_vector_type(4)));

__device__ __forceinline__ f32x4 mfma16(bf16x8 a, bf16x8 b, f32x4 c) {
  return __builtin_amdgcn_mfma_f32_16x16x32_bf16(a, b, c, 0, 0, 0);
}

__device__ __forceinline__ void gload16(const void* g, void* l) {
  __builtin_amdgcn_global_load_lds(
      (const __attribute__((address_space(1))) void*)g,
      (__attribute__((address_space(3))) void*)l, 16, 0, 0);
}

// ---------------- ternary threshold: deterministic fp64 reduction (fused, 6 weights) --------
__global__ void abssum_all(const float* __restrict__ W0, const float* __restrict__ W1_,
                           const float* __restrict__ W2_, const float* __restrict__ W3,
                           const float* __restrict__ W4, const float* __restrict__ W5,
                           double* __restrict__ partial) {
  __shared__ double sd[256];
  const int w = blockIdx.y, tid = threadIdx.x;
  const float* W = (w == 0) ? W0 : (w == 1) ? W1_ : (w == 2) ? W2_ : (w == 3) ? W3 : (w == 4) ? W4 : W5;
  const int n4 = (w < 4) ? 1048576 : 4194304;
  double s = 0.0;
  for (int i = blockIdx.x * 256 + tid; i < n4; i += 262144) {
    float4 v = ((const float4*)W)[i];
    s += (double)fabsf(v.x); s += (double)fabsf(v.y);
    s += (double)fabsf(v.z); s += (double)fabsf(v.w);
  }
  sd[tid] = s; __syncthreads();
  for (int st = 128; st > 0; st >>= 1) { if (tid < st) sd[tid] += sd[tid + st]; __syncthreads(); }
  if (tid == 0) partial[w * 1024 + blockIdx.x] = sd[0];
}

__global__ void abssum_fin(const double* __restrict__ partial, double* __restrict__ sums) {
  __shared__ double sd[256];
  const int tid = threadIdx.x;
  const double* p = partial + blockIdx.x * 1024;
  double s = p[tid] + p[tid + 256] + p[tid + 512] + p[tid + 768];
  sd[tid] = s; __syncthreads();
  for (int st = 128; st > 0; st >>= 1) { if (tid < st) sd[tid] += sd[tid + st]; __syncthreads(); }
  if (tid == 0) sums[blockIdx.x] = sd[0];
}

// ternarize Wq,Wk,Wv,Wo (4 x 4.19M elems) into one contiguous wt in a single launch
__global__ void ternarize4(const float* __restrict__ W0, const float* __restrict__ W1_,
                           const float* __restrict__ W2_, const float* __restrict__ W3,
                           bf16_t* __restrict__ out, const double* __restrict__ sums) {
  const int w = blockIdx.x >> 12;
  const float* W = (w == 0) ? W0 : (w == 1) ? W1_ : (w == 2) ? W2_ : W3;
  const double thr = sums[w] / 4194304.0;
  const int i = (blockIdx.x & 4095) * 256 + threadIdx.x;
  float4 v = ((const float4*)W)[i];
  bf16x4 o;
  float t;
  t = ((double)fabsf(v.x) > thr) ? (v.x > 0.f ? 1.f : -1.f) : 0.f; o[0] = (bf16_t)t;
  t = ((double)fabsf(v.y) > thr) ? (v.y > 0.f ? 1.f : -1.f) : 0.f; o[1] = (bf16_t)t;
  t = ((double)fabsf(v.z) > thr) ? (v.z > 0.f ? 1.f : -1.f) : 0.f; o[2] = (bf16_t)t;
  t = ((double)fabsf(v.w) > thr) ? (v.w > 0.f ? 1.f : -1.f) : 0.f; o[3] = (bf16_t)t;
  *(bf16x4*)&out[(size_t)w * 4194304 + (size_t)i * 4] = o;
}

__global__ void ternarize_k(const float* __restrict__ W, bf16_t* __restrict__ out,
                            const double* __restrict__ sum, double n) {
  const double thr = sum[0] / n;
  const int i = blockIdx.x * 256 + threadIdx.x;
  float4 v = ((const float4*)W)[i];
  bf16x4 o;
  float t;
  t = ((double)fabsf(v.x) > thr) ? (v.x > 0.f ? 1.f : -1.f) : 0.f; o[0] = (bf16_t)t;
  t = ((double)fabsf(v.y) > thr) ? (v.y > 0.f ? 1.f : -1.f) : 0.f; o[1] = (bf16_t)t;
  t = ((double)fabsf(v.z) > thr) ? (v.z > 0.f ? 1.f : -1.f) : 0.f; o[2] = (bf16_t)t;
  t = ((double)fabsf(v.w) > thr) ? (v.w > 0.f ? 1.f : -1.f) : 0.f; o[3] = (bf16_t)t;
  *(bf16x4*)&out[(size_t)i * 4] = o;
}

// ---------------- x -> interleaved hi/lo: xhl[t] = [ xh row (2048) | xl row (2048) ] ----------
__global__ void split_x_k(const float* __restrict__ X, bf16_t* __restrict__ xhl) {
  const int i = blockIdx.x * 256 + threadIdx.x;   // float4 idx; 512 per token row
  const int t = i >> 9, col = (i & 511) * 4;
  float4 v = ((const float4*)X)[i];
  bf16x4 h, l;
  h[0] = (bf16_t)v.x; l[0] = (bf16_t)(v.x - (float)h[0]);
  h[1] = (bf16_t)v.y; l[1] = (bf16_t)(v.y - (float)h[1]);
  h[2] = (bf16_t)v.z; l[2] = (bf16_t)(v.z - (float)h[2]);
  h[3] = (bf16_t)v.w; l[3] = (bf16_t)(v.w - (float)h[3]);
  *(bf16x4*)&xhl[(size_t)t * 4096 + col] = h;
  *(bf16x4*)&xhl[(size_t)t * 4096 + 2048 + col] = l;
}

// ---------------- GEMM v3: m201-style 2-phase (V, O-proj) ----------------
// lda = A row stride (pow2, >= K reads used).
template <int EPI>
__global__ __launch_bounds__(512, 2) void gemmP(
    const bf16_t* __restrict__ Ah, const bf16_t* __restrict__ Bw,
    void* __restrict__ C0, int N, int K, int lda) {
  constexpr int BM = 128;
  __shared__ __align__(16) bf16_t sA[3][BM * 64];
  __shared__ __align__(16) bf16_t sB[3][256 * 64];

  const int tid = threadIdx.x;
  const int wid = tid >> 6, lane = tid & 63, lr = lane & 15, lg = lane >> 4;
  const int wr = wid >> 2, wc = wid & 3;
  const size_t Ks = (size_t)K;

  const int nwg = gridDim.x * gridDim.y;
  const int bid0 = blockIdx.y * gridDim.x + blockIdx.x;
  const int swz = (bid0 & 7) * (nwg >> 3) + (bid0 >> 3);
  const int bx = swz % gridDim.x, by = swz / gridDim.x;
  const size_t m0 = (size_t)by * BM, n0 = (size_t)bx * 256;
  const int nt = K / 64;

  f32x4 acc[4][4] = {};

  auto STAGEH = [&](int bi, int kt, int half) {
    const size_t ko = (size_t)kt * 64;
    if (half == 0) {
#pragma unroll
      for (int i = 0; i < 2; i++) {
        const int t = i * 512 + tid;
        const int r = t >> 3;
        const int su = (t & 7) ^ (r & 7);
        const int lo = (i * 512 + wid * 64) * 8;
        gload16(Ah + (m0 + r) * (size_t)lda + ko + su * 8, (void*)&sA[bi][lo]);
      }
      {
        const int r = tid >> 3;
        const int su = (tid & 7) ^ (r & 7);
        gload16(Bw + (n0 + r) * Ks + ko + su * 8, (void*)&sB[bi][(wid * 64) * 8]);
      }
    } else {
#pragma unroll
      for (int i = 1; i < 4; i++) {
        const int t = i * 512 + tid;
        const int r = t >> 3;
        const int su = (t & 7) ^ (r & 7);
        gload16(Bw + (n0 + r) * Ks + ko + su * 8, (void*)&sB[bi][(i * 512 + wid * 64) * 8]);
      }
    }
  };
  auto LDA = [&](const bf16_t* base, int m, int k) -> bf16x8 {
    const int row = wr * 64 + m * 16 + lr;
    const int u = (k * 4 + lg) ^ (lr & 7);
    return *(const bf16x8*)&base[row * 64 + u * 8];
  };
  auto LDB = [&](const bf16_t* base, int n, int k) -> bf16x8 {
    const int row = wc * 64 + n * 16 + lr;
    const int u = (k * 4 + lg) ^ (lr & 7);
    return *(const bf16x8*)&base[row * 64 + u * 8];
  };

  STAGEH(0, 0, 0); STAGEH(0, 0, 1);
  STAGEH(1, 1, 0); STAGEH(1, 1, 1);
  asm volatile("s_waitcnt vmcnt(6)" ::: "memory");
  __builtin_amdgcn_s_barrier();

  int bc = 0, bs = 2;
  for (int kt = 0; kt < nt; kt++) {
    const bool pf = (kt + 2 < nt);
    bf16x8 a[4][2], bfr[4][2];
#pragma unroll
    for (int m = 0; m < 4; m++)
#pragma unroll
      for (int k = 0; k < 2; k++) a[m][k] = LDA(&sA[bc][0], m, k);
#pragma unroll
    for (int n = 0; n < 2; n++)
#pragma unroll
      for (int k = 0; k < 2; k++) bfr[n][k] = LDB(&sB[bc][0], n, k);
    if (pf) STAGEH(bs, kt + 2, 0);
    __builtin_amdgcn_s_barrier();
    asm volatile("s_waitcnt lgkmcnt(0)" ::: "memory");
    __builtin_amdgcn_sched_barrier(0);
    __builtin_amdgcn_s_setprio(1);
#pragma unroll
    for (int k = 0; k < 2; k++)
#pragma unroll
      for (int m = 0; m < 4; m++)
#pragma unroll
        for (int n = 0; n < 2; n++) acc[m][n] = mfma16(a[m][k], bfr[n][k], acc[m][n]);
    __builtin_amdgcn_s_setprio(0);
    __builtin_amdgcn_s_barrier();
#pragma unroll
    for (int n = 0; n < 2; n++)
#pragma unroll
      for (int k = 0; k < 2; k++) bfr[n + 2][k] = LDB(&sB[bc][0], n + 2, k);
    if (pf) STAGEH(bs, kt + 2, 1);
    if (kt + 1 < nt) {
      if (pf) asm volatile("s_waitcnt vmcnt(6)" ::: "memory");
      else    asm volatile("s_waitcnt vmcnt(0)" ::: "memory");
    }
    __builtin_amdgcn_s_barrier();
    asm volatile("s_waitcnt lgkmcnt(0)" ::: "memory");
    __builtin_amdgcn_sched_barrier(0);
    __builtin_amdgcn_s_setprio(1);
#pragma unroll
    for (int k = 0; k < 2; k++)
#pragma unroll
      for (int m = 0; m < 4; m++)
#pragma unroll
        for (int n = 0; n < 2; n++) acc[m][n + 2] = mfma16(a[m][k], bfr[n + 2][k], acc[m][n + 2]);
    __builtin_amdgcn_s_setprio(0);
    __builtin_amdgcn_s_barrier();
    bc = (bc + 1 == 3) ? 0 : bc + 1;
    bs = (bs + 1 == 3) ? 0 : bs + 1;
  }

  const int row0 = (int)m0 + wr * 64, colb = (int)n0 + wc * 64;
#pragma unroll
  for (int m = 0; m < 4; m++)
#pragma unroll
    for (int n = 0; n < 4; n++)
#pragma unroll
      for (int j = 0; j < 4; j++) {
        const int r = row0 + m * 16 + lg * 4 + j;
        const int c = colb + n * 16 + lr;
        const float v = acc[m][n][j];
        if constexpr (EPI == 1) {
          const int bb = r >> 11, ss = r & 2047;
          ((bf16_t*)C0)[((size_t)bb * 2048 + c) * 2048 + ss] = (bf16_t)v;
        } else {
          ((float*)C0)[(size_t)r * N + c] = v;
        }
      }
}

// ---------------- GEMM 256x256, 8-phase m201 schedule (QK / FF1 / FF2-splitK) -------------
// EPI: 0 = split hi/lo bf16 store, 3 = relu bf16 store, 4 = f32 store to (kh? C1 : C0).
template <int EPI, int MB>
__global__ __launch_bounds__(512, 2) void gemm256(
    const bf16_t* __restrict__ A, const bf16_t* __restrict__ Bw,
    void* __restrict__ C0, void* __restrict__ C1,
    int N, int K, int lda, int ldb) {
  __shared__ __align__(16) bf16_t sA[2][256 * 64];
  __shared__ __align__(16) bf16_t sB[2][256 * 64];
  const int tid = threadIdx.x;
  const int wid = tid >> 6, lane = tid & 63, lr = lane & 15, lg = lane >> 4;
  const int wr = wid >> 2, wc = wid & 3;   // 2M x 4N waves; per-wave 128x64
  const int nwg = gridDim.x * gridDim.y;
  const int bid0 = blockIdx.y * gridDim.x + blockIdx.x;
  const int swz = (bid0 & 7) * (nwg >> 3) + (bid0 >> 3);
  const int bx = swz % gridDim.x, by = swz / gridDim.x;
  const int mt = by & ((1 << MB) - 1), kh = by >> MB;
  const int koff = kh * K;
  const size_t m0 = (size_t)mt * 256, n0 = (size_t)bx * 256;
  const int nt = K / 64;
  const bf16_t* Abase = A + m0 * (size_t)lda;
  const bf16_t* Bbase = Bw + n0 * (size_t)ldb;

  f32x4 acc[8][4] = {};

  auto SG = [&](const bf16_t* base, bf16_t* dst, int kt, int h, int ld) {
    const size_t co = (size_t)((kt * 64 + koff) & (ld - 1));
#pragma unroll
    for (int i = 0; i < 2; i++) {
      const int e = (2 * h + i) * 512 + tid;
      const int r = e >> 3;
      const int su = (tid & 7) ^ (r & 7);
      gload16(base + (size_t)r * ld + co + su * 8,
              (void*)&dst[((2 * h + i) * 512 + wid * 64) * 8]);
    }
  };
  auto LDA = [&](int bi, int m, int k) -> bf16x8 {
    const int row = wr * 128 + m * 16 + lr;
    const int u = (k * 4 + lg) ^ (lr & 7);
    return *(const bf16x8*)&sA[bi][row * 64 + u * 8];
  };
  auto LDB = [&](int bi, int n, int k) -> bf16x8 {
    const int row = wc * 64 + n * 16 + lr;
    const int u = (k * 4 + lg) ^ (lr & 7);
    return *(const bf16x8*)&sB[bi][row * 64 + u * 8];
  };

  // prologue: tile0 full; tile1 B0,B1,A0 (A1 comes at kt0.Q1)
  SG(Abase, sA[0], 0, 0, lda); SG(Abase, sA[0], 0, 1, lda);
  SG(Bbase, sB[0], 0, 0, ldb); SG(Bbase, sB[0], 0, 1, ldb);
  SG(Bbase, sB[1], 1, 0, ldb); SG(Bbase, sB[1], 1, 1, ldb); SG(Abase, sA[1], 1, 0, lda);
  asm volatile("s_waitcnt vmcnt(6)" ::: "memory");
  __builtin_amdgcn_s_barrier();

  for (int kt = 0; kt < nt; kt++) {
    const int bi = kt & 1, bn = bi ^ 1;
    bf16x8 a[4][2], b[4][2];
    // ---- Q1: m0-3 x n0-1 ----
#pragma unroll
    for (int m = 0; m < 4; m++)
#pragma unroll
      for (int k = 0; k < 2; k++) a[m][k] = LDA(bi, m, k);
#pragma unroll
    for (int n = 0; n < 2; n++)
#pragma unroll
      for (int k = 0; k < 2; k++) b[n][k] = LDB(bi, n, k);
    if (kt + 1 < nt) SG(Abase, sA[bn], kt + 1, 1, lda);   // deferred A1 of next tile
    __builtin_amdgcn_s_barrier();
    asm volatile("s_waitcnt lgkmcnt(0)" ::: "memory");
    __builtin_amdgcn_sched_barrier(0);
    __builtin_amdgcn_s_setprio(1);
#pragma unroll
    for (int k = 0; k < 2; k++)
#pragma unroll
      for (int m = 0; m < 4; m++)
#pragma unroll
        for (int n = 0; n < 2; n++) acc[m][n] = mfma16(a[m][k], b[n][k], acc[m][n]);
    __builtin_amdgcn_s_setprio(0);
    __builtin_amdgcn_s_barrier();
    // ---- Q2: m0-3 x n2-3 ----
#pragma unroll
    for (int n = 0; n < 2; n++)
#pragma unroll
      for (int k = 0; k < 2; k++) b[n + 2][k] = LDB(bi, n + 2, k);
    if (kt + 2 < nt) SG(Bbase, sB[bi], kt + 2, 0, ldb);
    __builtin_amdgcn_s_barrier();
    asm volatile("s_waitcnt lgkmcnt(0)" ::: "memory");
    __builtin_amdgcn_sched_barrier(0);
    __builtin_amdgcn_s_setprio(1);
#pragma unroll
    for (int k = 0; k < 2; k++)
#pragma unroll
      for (int m = 0; m < 4; m++)
#pragma unroll
        for (int n = 0; n < 2; n++) acc[m][n + 2] = mfma16(a[m][k], b[n + 2][k], acc[m][n + 2]);
    __builtin_amdgcn_s_setprio(0);
    __builtin_amdgcn_s_barrier();
    // ---- Q3: m4-7 x n2-3 ----
#pragma unroll
    for (int m = 0; m < 4; m++)
#pragma unroll
      for (int k = 0; k < 2; k++) a[m][k] = LDA(bi, m + 4, k);
    if (kt + 2 < nt) SG(Bbase, sB[bi], kt + 2, 1, ldb);
    __builtin_amdgcn_s_barrier();
    asm volatile("s_waitcnt lgkmcnt(0)" ::: "memory");
    __builtin_amdgcn_sched_barrier(0);
    __builtin_amdgcn_s_setprio(1);
#pragma unroll
    for (int k = 0; k < 2; k++)
#pragma unroll
      for (int m = 0; m < 4; m++)
#pragma unroll
        for (int n = 0; n < 2; n++) acc[m + 4][n + 2] = mfma16(a[m][k], b[n + 2][k], acc[m + 4][n + 2]);
    __builtin_amdgcn_s_setprio(0);
    __builtin_amdgcn_s_barrier();
    // ---- Q4: m4-7 x n0-1 (a,b already in regs) ----
    if (kt + 2 < nt) SG(Abase, sA[bi], kt + 2, 0, lda);
    __builtin_amdgcn_s_setprio(1);
#pragma unroll
    for (int k = 0; k < 2; k++)
#pragma unroll
      for (int m = 0; m < 4; m++)
#pragma unroll
        for (int n = 0; n < 2; n++) acc[m + 4][n] = mfma16(a[m][k], b[n][k], acc[m + 4][n]);
    __builtin_amdgcn_s_setprio(0);
    if (kt + 1 < nt) {
      if (kt + 2 < nt) asm volatile("s_waitcnt vmcnt(6)" ::: "memory");
      else             asm volatile("s_waitcnt vmcnt(0)" ::: "memory");
    }
    __builtin_amdgcn_s_barrier();
  }

  const int row0 = (int)m0 + wr * 128, colb = (int)n0 + wc * 64;
#pragma unroll
  for (int m = 0; m < 8; m++)
#pragma unroll
    for (int n = 0; n < 4; n++)
#pragma unroll
      for (int j = 0; j < 4; j++) {
        const int r = row0 + m * 16 + lg * 4 + j;
        const int c = colb + n * 16 + lr;
        const float v = acc[m][n][j];
        if constexpr (EPI == 0) {
          bf16_t hi = (bf16_t)v;
          ((bf16_t*)C0)[(size_t)r * N + c] = hi;
          ((bf16_t*)C1)[(size_t)r * N + c] = (bf16_t)(v - (float)hi);
        } else if constexpr (EPI == 4) {
          float* dst = (float*)(kh ? C1 : C0);
          dst[(size_t)r * N + c] = v;
        } else {
          ((bf16_t*)C0)[(size_t)r * N + c] = (bf16_t)fmaxf(v, 0.f);
        }
      }
}

// ---------------- flash attention v10 (proven: Kh+Kl staged, single-drain P) --------
__global__ __launch_bounds__(256, 2) void attn_k(
    const bf16_t* __restrict__ qh, const bf16_t* __restrict__ ql,
    const bf16_t* __restrict__ kh, const bf16_t* __restrict__ kl,
    const bf16_t* __restrict__ vT, bf16_t* __restrict__ out) {
  __shared__ __align__(16) bf16_t sKh[2 * 8192];   // 2 x [64][128]; epilogue scratch
  __shared__ __align__(16) bf16_t sKl[2 * 8192];
  __shared__ __align__(16) bf16_t plds[4][2048];   // per-wave P [2 tiles][16 q][64 kv]

  const int fid = blockIdx.y * 16 + blockIdx.x;
  const int qt = fid >> 5;
  const int bh = (fid & 7) * 4 + ((fid >> 3) & 3);
  const int b = bh >> 4, h = bh & 15;
  const int wv = threadIdx.x >> 6, lane = threadIdx.x & 63, lr = lane & 15, lg = lane >> 4;
  const size_t tok0 = (size_t)b * 2048 + qt * 128 + wv * 16;  // tile0; tile1 = +64
  bf16_t* pw = &plds[wv][0];

  auto STAGE = [&](int bufi, int kv0n) {
#pragma unroll
    for (int i = 0; i < 4; i++) {
      const int tt = wv * 4 + i;
      const int r = tt * 4 + (lane >> 4);
      const int ce = ((lane & 15) ^ (r & 7)) * 8;
      const size_t gofs = ((size_t)b * 2048 + kv0n + r) * 4096 + h * 128 + ce;
      gload16(kh + gofs, (void*)&sKh[bufi * 8192 + tt * 512]);
      gload16(kl + gofs, (void*)&sKl[bufi * 8192 + tt * 512]);
    }
  };

  bf16x8 qhf[2][4], qlf[2][4];
#pragma unroll
  for (int t = 0; t < 2; t++) {
    const bf16_t* qp = qh + (tok0 + t * 64 + lr) * 4096 + h * 128 + lg * 8;
    const bf16_t* qp2 = ql + (tok0 + t * 64 + lr) * 4096 + h * 128 + lg * 8;
#pragma unroll
    for (int ks = 0; ks < 4; ks++) {
      qhf[t][ks] = *(const bf16x8*)(qp + ks * 32);
      qlf[t][ks] = *(const bf16x8*)(qp2 + ks * 32);
    }
  }
  f32x4 oacc[2][8] = {};           // [tile][dt]: row d=dt*16+lg*4+j, col q=lr
  float mrun[2] = {-1e30f, -1e30f};
  float lrun[2] = {0.f, 0.f};
  const bf16_t* vbase = vT + ((size_t)b * 2048 + h * 128) * 2048;
  const float sc = 0.08838834764831845f;
  const int swz8 = 2 * (lr & 7);

  STAGE(0, 0);
  for (int c = 0; c < 32; c++) {
    const int kv0 = c * 64;
    if (c + 1 < 32) {
      STAGE((c + 1) & 1, kv0 + 64);
      asm volatile("s_waitcnt vmcnt(8)" ::: "memory");
    } else {
      asm volatile("s_waitcnt vmcnt(0)" ::: "memory");
    }
    __builtin_amdgcn_s_barrier();

    const int bufo = (c & 1) * 8192;
    // ---- swapped QK^T: lane holds 16 k-values for one q-row (q = lr) ----
    f32x4 s[2][4] = {};
    __builtin_amdgcn_s_setprio(1);
#pragma unroll
    for (int nb = 0; nb < 4; nb++) {
      const int rbase = bufo + (nb * 16 + lr) * 128;
#pragma unroll
      for (int ks = 0; ks < 4; ks++) {
        const int u = (((ks * 4 + lg) ^ (lr & 7)) * 8);
        bf16x8 kf = *(const bf16x8*)&sKh[rbase + u];
        bf16x8 kg = *(const bf16x8*)&sKl[rbase + u];
        s[0][nb] = mfma16(kf, qhf[0][ks], s[0][nb]);
        s[1][nb] = mfma16(kf, qhf[1][ks], s[1][nb]);
        s[0][nb] = mfma16(kf, qlf[0][ks], s[0][nb]);
        s[1][nb] = mfma16(kf, qlf[1][ks], s[1][nb]);
        s[0][nb] = mfma16(kg, qhf[0][ks], s[0][nb]);
        s[1][nb] = mfma16(kg, qhf[1][ks], s[1][nb]);
      }
    }
    __builtin_amdgcn_s_setprio(0);

    // ---- softmax both tiles; batched P writes; ONE drain; reads ----
    float resc[2];
    bool skip[2];
#pragma unroll
    for (int t = 0; t < 2; t++) {
#pragma unroll
      for (int nb = 0; nb < 4; nb++) s[t][nb] *= sc;
      f32x4 m4 = __builtin_elementwise_max(
          __builtin_elementwise_max(s[t][0], s[t][1]),
          __builtin_elementwise_max(s[t][2], s[t][3]));
      float mx = fmaxf(fmaxf(m4[0], m4[1]), fmaxf(m4[2], m4[3]));
      mx = fmaxf(mx, __shfl_xor(mx, 16));
      mx = fmaxf(mx, __shfl_xor(mx, 32));
      skip[t] = (__all(mx <= mrun[t] + 8.f) != 0);  // defer-max (THR=8)
      float rs_ = 1.f;
      if (!skip[t]) {
        const float mnew = fmaxf(mrun[t], mx);
        rs_ = __expf(mrun[t] - mnew);
        mrun[t] = mnew;
      }
      resc[t] = rs_;
      float ls = 0.f;
#pragma unroll
      for (int nb = 0; nb < 4; nb++) {
        bf16x4 pk;
#pragma unroll
        for (int j = 0; j < 4; j++) {
          const float p = __expf(s[t][nb][j] - mrun[t]);
          ls += p;
          pk[j] = (bf16_t)p;
        }
        const int s8 = (4 * nb + lg) ^ swz8;
        *(bf16x4*)&pw[t * 1024 + lr * 64 + s8 * 4] = pk;
      }
      ls += __shfl_xor(ls, 16);
      ls += __shfl_xor(ls, 32);
      lrun[t] = lrun[t] * rs_ + ls;
    }
    asm volatile("s_waitcnt lgkmcnt(0)" ::: "memory");
    __builtin_amdgcn_sched_barrier(0);
    bf16x8 pfr[2][2];
#pragma unroll
    for (int t = 0; t < 2; t++)
#pragma unroll
      for (int kc = 0; kc < 2; kc++) {
        const int se = (8 * kc + 2 * lg) ^ swz8;
        pfr[t][kc] = *(const bf16x8*)&pw[t * 1024 + lr * 64 + se * 4];
      }
    if (!skip[0]) {
#pragma unroll
      for (int dt = 0; dt < 8; dt++) oacc[0][dt] *= resc[0];
    }
    if (!skip[1]) {
#pragma unroll
      for (int dt = 0; dt < 8; dt++) oacc[1][dt] *= resc[1];
    }

    // ---- PV swapped: A = V^T rows (d), shared across tiles ----
    const bf16_t* vp = vbase + kv0 + lg * 8;
    __builtin_amdgcn_s_setprio(1);
#pragma unroll
    for (int dt = 0; dt < 8; dt++) {
      const bf16_t* vr = vp + (size_t)(dt * 16 + lr) * 2048;
      bf16x8 v0 = *(const bf16x8*)(vr);
      bf16x8 v1 = *(const bf16x8*)(vr + 32);
      oacc[0][dt] = mfma16(v0, pfr[0][0], oacc[0][dt]);
      oacc[1][dt] = mfma16(v0, pfr[1][0], oacc[1][dt]);
      oacc[0][dt] = mfma16(v1, pfr[0][1], oacc[0][dt]);
      oacc[1][dt] = mfma16(v1, pfr[1][1], oacc[1][dt]);
    }
    __builtin_amdgcn_s_setprio(0);
    asm volatile("" ::: "memory");
    __builtin_amdgcn_s_barrier();
  }

  // ---- epilogue: padded per-wave transpose region in sKh (K data dead) ----
  {
    bf16_t* ep = &sKh[wv * 2176];                // [16 q][136 pad] bf16
    const int q = lane >> 2, c4 = lane & 3;
    const int qs = 2 * (q & 7);
#pragma unroll
    for (int t = 0; t < 2; t++) {
      const float inv = 1.f / lrun[t];
#pragma unroll
      for (int dt = 0; dt < 8; dt++) {
        bf16x4 pk;
#pragma unroll
        for (int j = 0; j < 4; j++) pk[j] = (bf16_t)(oacc[t][dt][j] * inv);
        const int s5 = (4 * dt + lg) ^ swz8;
        *(bf16x4*)&ep[lr * 136 + s5 * 4] = pk;
      }
      asm volatile("s_waitcnt lgkmcnt(0)" ::: "memory");
      __builtin_amdgcn_sched_barrier(0);
      bf16_t* orow = out + (tok0 + t * 64 + q) * 2048 + h * 128 + c4 * 32;
#pragma unroll
      for (int i = 0; i < 4; i++) {
        const int se = (c4 * 8 + 2 * i) ^ qs;
        bf16x8 vv = *(const bf16x8*)&ep[q * 136 + se * 4];
        *(bf16x8*)(orow + i * 8) = vv;
      }
      asm volatile("s_waitcnt lgkmcnt(0)" ::: "memory");
    }
  }
}

// ---------------- fused residual + LayerNorm (f32 X,R; optional f32/bf16 outs) -------------
__global__ __launch_bounds__(256) void ln_k(
    const float* __restrict__ X, const float* __restrict__ R,
    const float* __restrict__ G, const float* __restrict__ Bt,
    float* __restrict__ O32, bf16_t* __restrict__ O16) {
  const int t = blockIdx.x, tid = threadIdx.x;
  const float4* xp = (const float4*)(X + (size_t)t * 2048);
  const float4* rp = (const float4*)(R + (size_t)t * 2048);
  float4 v0 = xp[tid], w0 = rp[tid];
  float4 v1 = xp[tid + 256], w1 = rp[tid + 256];
  v0.x += w0.x; v0.y += w0.y; v0.z += w0.z; v0.w += w0.w;
  v1.x += w1.x; v1.y += w1.y; v1.z += w1.z; v1.w += w1.w;
  float sum = v0.x + v0.y + v0.z + v0.w + v1.x + v1.y + v1.z + v1.w;
  float sq = v0.x * v0.x + v0.y * v0.y + v0.z * v0.z + v0.w * v0.w +
             v1.x * v1.x + v1.y * v1.y + v1.z * v1.z + v1.w * v1.w;
  for (int d = 1; d < 64; d <<= 1) { sum += __shfl_xor(sum, d); sq += __shfl_xor(sq, d); }
  __shared__ float s1[4], s2[4];
  const int wv = tid >> 6, lane = tid & 63;
  if (lane == 0) { s1[wv] = sum; s2[wv] = sq; }
  __syncthreads();
  const float tot = s1[0] + s1[1] + s1[2] + s1[3];
  const float tsq = s2[0] + s2[1] + s2[2] + s2[3];
  const float mu = tot * (1.f / 2048.f);
  const float var = tsq * (1.f / 2048.f) - mu * mu;
  const float rs = 1.f / sqrtf(var + 1e-5f);
  const float4* gp = (const float4*)G;
  const float4* bp = (const float4*)Bt;
  float4 g0 = gp[tid], g1v = gp[tid + 256], b0 = bp[tid], b1v = bp[tid + 256];
  float4 o0, o1;
  o0.x = (v0.x - mu) * rs * g0.x + b0.x; o0.y = (v0.y - mu) * rs * g0.y + b0.y;
  o0.z = (v0.z - mu) * rs * g0.z + b0.z; o0.w = (v0.w - mu) * rs * g0.w + b0.w;
  o1.x = (v1.x - mu) * rs * g1v.x + b1v.x; o1.y = (v1.y - mu) * rs * g1v.y + b1v.y;
  o1.z = (v1.z - mu) * rs * g1v.z + b1v.z; o1.w = (v1.w - mu) * rs * g1v.w + b1v.w;
  if (O32) {
    ((float4*)(O32 + (size_t)t * 2048))[tid] = o0;
    ((float4*)(O32 + (size_t)t * 2048))[tid + 256] = o1;
  }
  if (O16) {
    bf16x4 h0, h1;
    h0[0] = (bf16_t)o0.x; h0[1] = (bf16_t)o0.y; h0[2] = (bf16_t)o0.z; h0[3] = (bf16_t)o0.w;
    h1[0] = (bf16_t)o1.x; h1[1] = (bf16_t)o1.y; h1[2] = (bf16_t)o1.z; h1[3] = (bf16_t)o1.w;
    *(bf16x4*)&O16[(size_t)t * 2048 + tid * 4] = h0;
    *(bf16x4*)&O16[(size_t)t * 2048 + 1024 + tid * 4] = h1;
  }
}

// ---------------- LN2: bf16 X + two f32 residual partials -> f32 out ----------------
__global__ __launch_bounds__(256) void ln2_k(
    const bf16_t* __restrict__ Xb, const float* __restrict__ R0, const float* __restrict__ R1,
    const float* __restrict__ G, const float* __restrict__ Bt, float* __restrict__ out) {
  const int t = blockIdx.x, tid = threadIdx.x;
  bf16x4 x0 = *(const bf16x4*)&Xb[(size_t)t * 2048 + tid * 4];
  bf16x4 x1 = *(const bf16x4*)&Xb[(size_t)t * 2048 + 1024 + tid * 4];
  const float4* r0p = (const float4*)(R0 + (size_t)t * 2048);
  const float4* r1p = (const float4*)(R1 + (size_t)t * 2048);
  float4 a0 = r0p[tid], a1 = r0p[tid + 256];
  float4 c0 = r1p[tid], c1 = r1p[tid + 256];
  float4 v0, v1;
  v0.x = (float)x0[0] + a0.x + c0.x; v0.y = (float)x0[1] + a0.y + c0.y;
  v0.z = (float)x0[2] + a0.z + c0.z; v0.w = (float)x0[3] + a0.w + c0.w;
  v1.x = (float)x1[0] + a1.x + c1.x; v1.y = (float)x1[1] + a1.y + c1.y;
  v1.z = (float)x1[2] + a1.z + c1.z; v1.w = (float)x1[3] + a1.w + c1.w;
  float sum = v0.x + v0.y + v0.z + v0.w + v1.x + v1.y + v1.z + v1.w;
  float sq = v0.x * v0.x + v0.y * v0.y + v0.z * v0.z + v0.w * v0.w +
             v1.x * v1.x + v1.y * v1.y + v1.z * v1.z + v1.w * v1.w;
  for (int d = 1; d < 64; d <<= 1) { sum += __shfl_xor(sum, d); sq += __shfl_xor(sq, d); }
  __shared__ float s1[4], s2[4];
  const int wv = tid >> 6, lane = tid & 63;
  if (lane == 0) { s1[wv] = sum; s2[wv] = sq; }
  __syncthreads();
  const float tot = s1[0] + s1[1] + s1[2] + s1[3];
  const float tsq = s2[0] + s2[1] + s2[2] + s2[3];
  const float mu = tot * (1.f / 2048.f);
  const float var = tsq * (1.f / 2048.f) - mu * mu;
  const float rs = 1.f / sqrtf(var + 1e-5f);
  const float4* gp = (const float4*)G;
  const float4* bp = (const float4*)Bt;
  float4 g0 = gp[tid], g1v = gp[tid + 256], b0 = bp[tid], b1v = bp[tid + 256];
  float4 o0, o1;
  o0.x = (v0.x - mu) * rs * g0.x + b0.x; o0.y = (v0.y - mu) * rs * g0.y + b0.y;
  o0.z = (v0.z - mu) * rs * g0.z + b0.z; o0.w = (v0.w - mu) * rs * g0.w + b0.w;
  o1.x = (v1.x - mu) * rs * g1v.x + b1v.x; o1.y = (v1.y - mu) * rs * g1v.y + b1v.y;
  o1.z = (v1.z - mu) * rs * g1v.z + b1v.z; o1.w = (v1.w - mu) * rs * g1v.w + b1v.w;
  ((float4*)(out + (size_t)t * 2048))[tid] = o0;
  ((float4*)(out + (size_t)t * 2048))[tid + 256] = o1;
}

// ---------------- launch ----------------
extern "C" void kernel_launch(void* const* d_in, const int* in_sizes, int n_in,
                              void* d_out, int out_size, void* d_ws, size_t ws_size,
                              hipStream_t stream) {
  const float* x  = (const float*)d_in[0];
  const float* Wq = (const float*)d_in[1];
  const float* Wk = (const float*)d_in[2];
  const float* Wv = (const float*)d_in[3];
  const float* Wo = (const float*)d_in[4];
  const float* W1 = (const float*)d_in[5];
  const float* W2 = (const float*)d_in[6];
  const float* g1 = (const float*)d_in[7];
  const float* b1 = (const float*)d_in[8];
  const float* g2 = (const float*)d_in[9];
  const float* b2 = (const float*)d_in[10];
  float* out = (float*)d_out;
  char* ws = (char*)d_ws;

  constexpr size_t SZB = (size_t)4096 * 2048 * 2;  // 16.78 MB unit
  bf16_t* xhl = (bf16_t*)(ws + 0 * SZB);   // [4096][4096]; dead after V GEMM
  bf16_t* qkh = (bf16_t*)(ws + 2 * SZB);   // [4096][4096]: q | k (hi)
  bf16_t* qkl = (bf16_t*)(ws + 4 * SZB);   // same layout (lo)
  bf16_t* vt  = (bf16_t*)(ws + 6 * SZB);
  bf16_t* at  = (bf16_t*)(ws + 7 * SZB);
  float* o32  = (float*)(ws + 8 * SZB);
  bf16_t* wt  = (bf16_t*)(ws + 8 * SZB + (size_t)4096 * 2048 * 4);
  double* red = (double*)(ws + 8 * SZB + (size_t)4096 * 2048 * 4 + (size_t)8192 * 2048 * 2);
  double* sums = red + 8192;
  // aliases (phase-disjoint lifetimes)
  bf16_t* h1b = qkh;                       // over qkh (dead after attn)
  bf16_t* f1 = (bf16_t*)(ws + 4 * SZB);    // over qkl,vt,at (dead after O-proj)
  float* g32a = o32;                       // FF2 partial k-half 0 (over o32, dead after LN1)
  float* g32b = (float*)(ws + 0 * SZB);    // FF2 partial k-half 1 (over xhl, dead)
  (void)in_sizes; (void)n_in; (void)out_size; (void)ws_size;

  abssum_all<<<dim3(1024, 6), 256, 0, stream>>>(Wq, Wk, Wv, Wo, W1, W2, red);
  abssum_fin<<<6, 256, 0, stream>>>(red, sums);
  split_x_k<<<8192, 256, 0, stream>>>(x, xhl);
  ternarize4<<<16384, 256, 0, stream>>>(Wq, Wk, Wv, Wo, wt, sums);

  // merged Q+K via K-folding: A=[xh|xl] (lda 4096, K=4096), B wraps mod 2048
  gemm256<0, 8><<<dim3(16, 16), 512, 0, stream>>>(xhl, wt, qkh, qkl, 4096, 4096, 4096, 2048);
  // V (hi-only: K=2048 reads xh half of xhl; transposed store)
  gemmP<1><<<dim3(8, 32), 512, 0, stream>>>(xhl, wt + 8388608, vt, 2048, 2048, 4096);
  // attention
  attn_k<<<dim3(16, 32), 256, 0, stream>>>(qkh, qkl, qkh + 2048, qkl + 2048, vt, at);
  // O projection -> f32
  gemmP<2><<<dim3(8, 32), 512, 0, stream>>>(at, wt + 12582912, o32, 2048, 2048, 2048);
  // LN1 -> h1b (bf16 only)
  ln_k<<<4096, 256, 0, stream>>>(x, o32, g1, b1, nullptr, h1b);
  // FF1 + relu (256x256 8-phase)
  ternarize_k<<<16384, 256, 0, stream>>>(W1, wt, sums + 4, 16777216.0);
  gemm256<3, 8><<<dim3(32, 16), 512, 0, stream>>>(h1b, wt, f1, nullptr, 8192, 2048, 2048, 2048);
  // FF2 split-K (two 4096-halves, full chip): partials -> g32a / g32b
  ternarize_k<<<16384, 256, 0, stream>>>(W2, wt, sums + 5, 16777216.0);
  gemm256<4, 4><<<dim3(8, 32), 512, 0, stream>>>(f1, wt, g32a, g32b, 2048, 4096, 8192, 8192);
  // LN2: h1b + g32a + g32b -> out
  ln2_k<<<4096, 256, 0, stream>>>(h1b, g32a, g32b, g2, b2, out);
}